// Round 3
// baseline (5651.144 us; speedup 1.0000x reference)
//
#include <hip/hip_runtime.h>
#include <stdint.h>

// LSTM B=256,T=512,F=32,U=350; gates i,f,g(relu),o; h=o*relu(c); out=h.dw+db
//
// R3: weight-stationary, RMW-free flag sync, zero intra-block barriers.
//  - 16 batch groups x 11 col-blocks (128 thr = 2 waves). Wave (grp,tileg)
//    owns 16 cols x ALL 4 gates: 4 tiles x 12 kc x 16B/lane = 192 VGPRs of
//    bf16 weights, loaded once. Gates meet in registers (same acc slot across
//    the 4 gate accumulators) -> update phase is pure register math, no LDS,
//    no __syncthreads anywhere in the scan.
//  - Per-step sync: each wave release-stores its OWN monotonic version flag
//    (no atomics RMW, nothing serialized); pollers use 22 parallel acquire
//    loads (lane<22) + __all ballot. h ping-pong depth 2: flag==t+1 means
//    "wrote h_t AND finished reading h_{t-2} slot" -> overwrite-safe.
//  - h exchanged via global hbuf; same-XCD placement for a group's blocks
//    via grp = blockIdx&15 (round-robin XCD mapping) - perf heuristic; flag
//    ordering is agent-scope so correctness doesn't depend on it.
//  - Dense head: in-register shfl reduce -> atomicAdd into out (pre-init
//    to dense_b by init kernel). No reduce kernel, no wpart.

#define T_   512
#define F_   32
#define U_   350
#define G4   1400
#define NGRP 16
#define NB   16
#define NCB  11
#define KC   12
#define NT   88
#define HROW 352
#define NWV  22          // weight-owner waves (col tiles) per group

typedef __attribute__((ext_vector_type(8))) short  short8;
typedef __attribute__((ext_vector_type(4))) short  short4_;
typedef __attribute__((ext_vector_type(4))) float  float4_;

__device__ __forceinline__ short f2bf(float f) {
  union { float f; uint32_t u; } v; v.f = f;
  return (short)((v.u + 0x7FFFu + ((v.u >> 16) & 1u)) >> 16);
}

// ---- workspace layout (bytes) ----
#define SZ_W     (NT*KC*64*8*2u)                        // 1,081,344
#define OFF_XBF  (SZ_W)                                 // 256-aligned already
#define SZ_XBF   (256u*T_*F_*2u)                        // 8,388,608
#define OFF_HBUF (OFF_XBF + SZ_XBF)
#define SZ_HBUF  (NGRP*2u*NB*HROW*2u)                   // 360,448
#define OFF_FLG  (OFF_HBUF + SZ_HBUF)
#define SZ_FLG   (NGRP*64u*4u)                          // 4,096

// ---- prep: W_swz[kc][tile][lane][8] bf16 in MFMA B-fragment order ----
// tile = gate*22 + jt ; col_g = jt*16 + (lane&15) ; k = kc*32 + (lane>>4)*8 + jj
__global__ void prep_w(const float* __restrict__ kern,
                       const float* __restrict__ rk,
                       const float* __restrict__ bias,
                       short* __restrict__ wswz) {
  const int tile = blockIdx.x, lane = threadIdx.x;
  const int g = tile / 22, jt = tile % 22;
  const int colg = jt * 16 + (lane & 15);
  const int src = g * U_ + colg;
  const bool valid = (colg < U_);
  const int kbase = (lane >> 4) * 8;
  for (int kc = 0; kc < KC; ++kc) {
    short8 pack;
    #pragma unroll
    for (int jj = 0; jj < 8; ++jj) {
      int k = kc * 32 + kbase + jj;
      float v = 0.f;
      if (valid) {
        if (k < F_)            v = kern[k * G4 + src];
        else if (k < F_ + U_)  v = rk[(k - F_) * G4 + src];
        else if (k == F_ + U_) v = bias[src];
      }
      pack[jj] = f2bf(v);
    }
    *(short8*)(wswz + (((size_t)kc * NT + tile) * 64 + lane) * 8) = pack;
  }
}

// ---- prep: x f32 -> bf16 ([b][t][f], contiguous for 16B A-frag loads) ----
__global__ void prep_x(const float* __restrict__ x, short* __restrict__ xbf) {
  int i = (blockIdx.x * 256 + threadIdx.x) * 4;
  float4_ v = *(const float4_*)(x + i);
  short4_ o;
  #pragma unroll
  for (int jj = 0; jj < 4; ++jj) o[jj] = f2bf(v[jj]);
  *(short4_*)(xbf + i) = o;
}

// ---- init: flags=0, hbuf slot1 = h_{-1}=0 (+1.0 bias col), out=dense_b ----
__global__ void init_all(short* __restrict__ hbuf, uint32_t* __restrict__ flags,
                         const float* __restrict__ db, float* __restrict__ out) {
  int i = blockIdx.x * 256 + threadIdx.x;        // 131072 threads
  out[i] = db[0];
  if (i < NGRP * NB * HROW) {
    int grp = i / (NB * HROW), rem = i % (NB * HROW);
    int c = rem % HROW;
    hbuf[(grp * 2 + 1) * NB * HROW + rem] = (c == 350) ? (short)0x3F80 : (short)0;
  }
  if (i < NGRP * 64) flags[i] = 0;
}

// ---- main: persistent, 2 decoupled waves per block ----
__global__ __launch_bounds__(128, 1)
void lstm_kernel(const short* __restrict__ xbf, const short* __restrict__ wswz,
                 short* __restrict__ hbuf, uint32_t* __restrict__ flags,
                 const float* __restrict__ dense_w, float* __restrict__ out) {
  const int tid  = threadIdx.x;
  const int lane = tid & 63;
  const int wv   = tid >> 6;            // 0..1
  const int l15  = lane & 15;
  const int quad = lane >> 4;
  const int grp  = blockIdx.x & 15;     // same-XCD heuristic for the group
  const int j    = blockIdx.x >> 4;     // 0..10
  const int tileg = 2 * j + wv;         // this wave's col tile 0..21

  // weights -> registers (once): tiles {g*22 + tileg}, all kc
  short8 wreg[4][KC];
  #pragma unroll
  for (int g = 0; g < 4; ++g)
    #pragma unroll
    for (int kc = 0; kc < KC; ++kc)
      wreg[g][kc] = *(const short8*)(wswz +
          (((size_t)kc * NT + (g * 22 + tileg)) * 64 + lane) * 8);

  const int col = tileg * 16 + l15;               // gate-relative col 0..351
  const float dwv = (col < U_) ? dense_w[col] : 0.f;
  float cst[4] = {0.f, 0.f, 0.f, 0.f};

  const short* xrow = xbf + ((size_t)(grp * NB + l15) * T_) * F_ + quad * 8;
  short* hb = hbuf + (size_t)grp * 2 * NB * HROW;
  uint32_t* flg = (uint32_t*)flags + grp * 64;

  #pragma unroll 1
  for (int t = 0; t < T_; ++t) {
    short8 axf = *(const short8*)(xrow + t * F_);

    // kc=0 (x-only) MFMA before the spin — h-independent work
    float4_ acc[4];
    #pragma unroll
    for (int g = 0; g < 4; ++g) {
      float4_ z = (float4_){0.f, 0.f, 0.f, 0.f};
      acc[g] = __builtin_amdgcn_mfma_f32_16x16x32_bf16(axf, wreg[g][0], z, 0, 0, 0);
    }

    if (t > 0) {
      const uint32_t tv = (uint32_t)t;
      bool ok;
      do {
        uint32_t v = tv;
        if (lane < NWV)
          v = __hip_atomic_load(flg + lane, __ATOMIC_ACQUIRE,
                                __HIP_MEMORY_SCOPE_AGENT);
        ok = (bool)__all((int)(v >= tv));
      } while (!ok);
    }

    // h A-frags from slot (t-1)&1 == (t+1)&1
    const short* hrd = hb + ((size_t)((t + 1) & 1)) * NB * HROW
                          + (size_t)l15 * HROW + quad * 8;
    short8 ah[KC - 1];
    #pragma unroll
    for (int kc = 1; kc < KC; ++kc)
      ah[kc - 1] = *(const short8*)(hrd + 32 * (kc - 1));
    #pragma unroll
    for (int kc = 1; kc < KC; ++kc)
      #pragma unroll
      for (int g = 0; g < 4; ++g)
        acc[g] = __builtin_amdgcn_mfma_f32_16x16x32_bf16(ah[kc - 1], wreg[g][kc], acc[g], 0, 0, 0);

    // update: lane covers (rows quad*4+r, col). All 4 gates in registers.
    short* hwr = hb + ((size_t)(t & 1)) * NB * HROW;
    float hn[4];
    #pragma unroll
    for (int r = 0; r < 4; ++r) {
      float ig = __builtin_amdgcn_rcpf(1.f + __expf(-acc[0][r]));
      float fg = __builtin_amdgcn_rcpf(1.f + __expf(-acc[1][r]));
      float gg = fmaxf(acc[2][r], 0.f);
      float og = __builtin_amdgcn_rcpf(1.f + __expf(-acc[3][r]));
      float cn = fg * cst[r] + ig * gg;
      cst[r] = cn;
      hn[r] = og * fmaxf(cn, 0.f);
      short hs = f2bf(hn[r]);
      if (col == 350) hs = (short)0x3F80;        // bias-row input stays 1.0
      else if (col == 351) hs = 0;
      hwr[(quad * 4 + r) * HROW + col] = hs;
    }

    // publish: release store orders the h stores (wave-level vmcnt drain)
    if (lane == 0)
      __hip_atomic_store(flg + tileg, (uint32_t)(t + 1), __ATOMIC_RELEASE,
                         __HIP_MEMORY_SCOPE_AGENT);

    // dense head AFTER publish (off the critical path): sum over 16 cols
    #pragma unroll
    for (int r = 0; r < 4; ++r) {
      float s = hn[r] * dwv;
      s += __shfl_xor(s, 1); s += __shfl_xor(s, 2);
      s += __shfl_xor(s, 4); s += __shfl_xor(s, 8);
      if (l15 == 0)
        atomicAdd(out + (size_t)(grp * NB + quad * 4 + r) * T_ + t, s);
    }
  }
}

extern "C" void kernel_launch(void* const* d_in, const int* in_sizes, int n_in,
                              void* d_out, int out_size, void* d_ws, size_t ws_size,
                              hipStream_t stream) {
  const float* x    = (const float*)d_in[0];
  const float* kern = (const float*)d_in[1];
  const float* rk   = (const float*)d_in[2];
  const float* bias = (const float*)d_in[3];
  const float* dw   = (const float*)d_in[4];
  const float* db   = (const float*)d_in[5];
  float* out = (float*)d_out;

  char* ws = (char*)d_ws;
  short*    wswz = (short*)(ws);
  short*    xbf  = (short*)(ws + OFF_XBF);
  short*    hbuf = (short*)(ws + OFF_HBUF);
  uint32_t* flags= (uint32_t*)(ws + OFF_FLG);

  prep_w<<<NT, 64, 0, stream>>>(kern, rk, bias, wswz);
  prep_x<<<(256 * T_ * F_) / (256 * 4), 256, 0, stream>>>(x, xbf);
  init_all<<<(256 * T_) / 256, 256, 0, stream>>>(hbuf, flags, db, out);
  lstm_kernel<<<NGRP * NCB, 128, 0, stream>>>(xbf, wswz, hbuf, flags, dw, out);
}

// Round 4
// 4867.128 us; speedup vs baseline: 1.1611x; 1.1611x over previous
//
#include <hip/hip_runtime.h>
#include <stdint.h>

// LSTM B=256,T=512,F=32,U=350; gates i,f,g(relu),o; h=o*relu(c); out=h.dw+db
//
// R4: R3 structure + FORCED register residency for weights.
//  - Root cause of R2/R3 ~10us/step: allocator targeted 4 waves/EU (VGPR=128)
//    and re-streamed the 192-VGPR weight slice from L2 every step, serialized
//    into the MFMA chain. amdgpu_waves_per_eu(1,1) unlocks the 512-VGPR/lane
//    budget so the slice is loaded ONCE. Validate via VGPR_Count >= ~280.
//  - 16 groups x 11 col-blocks (128 thr = 2 waves); wave owns 16 cols x all
//    4 gates. Gates meet in registers; no LDS in the gate path; no barriers
//    in the scan loop.
//  - Sync: per-wave monotonic flag (release store); pollers: 22 relaxed loads
//    in parallel lanes + __all, then one acquire fence. h ping-pong depth 2.
//  - Dense head: shfl-reduce -> LDS[2][512][16]; bulk store to wpart after
//    the scan; reduce_out sums 11 partials + bias (validated in R2).

#define T_   512
#define F_   32
#define U_   350
#define G4   1400
#define NGRP 16
#define NB   16
#define NCB  11
#define KC   12
#define NT   88
#define HROW 352
#define NWV  22          // col-tile waves per group

typedef __attribute__((ext_vector_type(8))) short  short8;
typedef __attribute__((ext_vector_type(4))) short  short4_;
typedef __attribute__((ext_vector_type(4))) float  float4_;

__device__ __forceinline__ short f2bf(float f) {
  union { float f; uint32_t u; } v; v.f = f;
  return (short)((v.u + 0x7FFFu + ((v.u >> 16) & 1u)) >> 16);
}

// ---- workspace layout (bytes) ----
#define SZ_W     (NT*KC*64*8*2u)                        // 1,081,344
#define OFF_XBF  (SZ_W)
#define SZ_XBF   (256u*T_*F_*2u)                        // 8,388,608
#define OFF_HBUF (OFF_XBF + SZ_XBF)
#define SZ_HBUF  (NGRP*2u*NB*HROW*2u)                   // 360,448
#define OFF_FLG  (OFF_HBUF + SZ_HBUF)
#define SZ_FLG   (NGRP*64u*4u)                          // 4,096
#define OFF_WP   (OFF_FLG + SZ_FLG)
#define SZ_WP    (NGRP*NCB*NB*T_*4u)                    // 5,767,168

// ---- prep: W_swz[kc][tile][lane][8] bf16 in MFMA B-fragment order ----
__global__ void prep_w(const float* __restrict__ kern,
                       const float* __restrict__ rk,
                       const float* __restrict__ bias,
                       short* __restrict__ wswz) {
  const int tile = blockIdx.x, lane = threadIdx.x;
  const int g = tile / 22, jt = tile % 22;
  const int colg = jt * 16 + (lane & 15);
  const int src = g * U_ + colg;
  const bool valid = (colg < U_);
  const int kbase = (lane >> 4) * 8;
  for (int kc = 0; kc < KC; ++kc) {
    short8 pack;
    #pragma unroll
    for (int jj = 0; jj < 8; ++jj) {
      int k = kc * 32 + kbase + jj;
      float v = 0.f;
      if (valid) {
        if (k < F_)            v = kern[k * G4 + src];
        else if (k < F_ + U_)  v = rk[(k - F_) * G4 + src];
        else if (k == F_ + U_) v = bias[src];
      }
      pack[jj] = f2bf(v);
    }
    *(short8*)(wswz + (((size_t)kc * NT + tile) * 64 + lane) * 8) = pack;
  }
}

// ---- prep: x f32 -> bf16 ([b][t][f], contiguous 16B A-frag loads) ----
__global__ void prep_x(const float* __restrict__ x, short* __restrict__ xbf) {
  int i = (blockIdx.x * 256 + threadIdx.x) * 4;
  float4_ v = *(const float4_*)(x + i);
  short4_ o;
  #pragma unroll
  for (int jj = 0; jj < 4; ++jj) o[jj] = f2bf(v[jj]);
  *(short4_*)(xbf + i) = o;
}

// ---- init: flags=0, hbuf slot1 = h_{-1}=0 (+1.0 at bias col 350) ----
__global__ void init_all(short* __restrict__ hbuf, uint32_t* __restrict__ flags) {
  int i = blockIdx.x * 256 + threadIdx.x;        // 352*256 = 90112 threads
  int c = i % HROW;
  int grp = i / (NB * HROW), rem = i % (NB * HROW);
  hbuf[(grp * 2 + 1) * NB * HROW + rem] = (c == 350) ? (short)0x3F80 : (short)0;
  if (i < NGRP * 64) flags[i] = 0;
}

// ---- main: persistent, 2 decoupled waves per block, weights in VGPRs ----
__global__ __launch_bounds__(128)
__attribute__((amdgpu_waves_per_eu(1, 1)))
void lstm_kernel(const short* __restrict__ xbf, const short* __restrict__ wswz,
                 short* __restrict__ hbuf, uint32_t* __restrict__ flags,
                 const float* __restrict__ dense_w, float* __restrict__ wpart) {
  __shared__ float lds_part[2][T_][16];   // 64 KB dense-head partials

  const int tid  = threadIdx.x;
  const int lane = tid & 63;
  const int wv   = tid >> 6;            // 0..1
  const int l15  = lane & 15;
  const int quad = lane >> 4;
  const int grp  = blockIdx.x & 15;     // stride-16 keeps a group on one XCD
  const int j    = blockIdx.x >> 4;     // 0..10
  const int tileg = 2 * j + wv;         // this wave's col tile 0..21

  // weights -> registers ONCE: tiles {g*22 + tileg}, all kc (192 VGPRs)
  short8 wreg[4][KC];
  #pragma unroll
  for (int g = 0; g < 4; ++g)
    #pragma unroll
    for (int kc = 0; kc < KC; ++kc)
      wreg[g][kc] = *(const short8*)(wswz +
          (((size_t)kc * NT + (g * 22 + tileg)) * 64 + lane) * 8);

  const int col = tileg * 16 + l15;               // gate-relative col 0..351
  const float dwv = (col < U_) ? dense_w[col] : 0.f;
  float cst[4] = {0.f, 0.f, 0.f, 0.f};

  const short* xrow = xbf + ((size_t)(grp * NB + l15) * T_) * F_ + quad * 8;
  short* hb = hbuf + (size_t)grp * 2 * NB * HROW;
  uint32_t* flg = (uint32_t*)flags + grp * 64;

  #pragma unroll 1
  for (int t = 0; t < T_; ++t) {
    short8 axf = *(const short8*)(xrow + t * F_);

    // kc=0 (x-only) MFMA before the spin — h-independent
    float4_ acc[4];
    #pragma unroll
    for (int g = 0; g < 4; ++g) {
      float4_ z = (float4_){0.f, 0.f, 0.f, 0.f};
      acc[g] = __builtin_amdgcn_mfma_f32_16x16x32_bf16(axf, wreg[g][0], z, 0, 0, 0);
    }

    if (t > 0) {
      const uint32_t tv = (uint32_t)t;
      bool ok;
      do {
        uint32_t v = tv;
        if (lane < NWV)
          v = __hip_atomic_load(flg + lane, __ATOMIC_RELAXED,
                                __HIP_MEMORY_SCOPE_AGENT);
        ok = (bool)__all((int)(v >= tv));
      } while (!ok);
      __builtin_amdgcn_fence(__ATOMIC_ACQUIRE, "agent");
    }

    // h A-frags from slot (t-1)&1 == (t+1)&1
    const short* hrd = hb + ((size_t)((t + 1) & 1)) * NB * HROW
                          + (size_t)l15 * HROW + quad * 8;
    short8 ah[KC - 1];
    #pragma unroll
    for (int kc = 1; kc < KC; ++kc)
      ah[kc - 1] = *(const short8*)(hrd + 32 * (kc - 1));
    #pragma unroll
    for (int kc = 1; kc < KC; ++kc)
      #pragma unroll
      for (int g = 0; g < 4; ++g)
        acc[g] = __builtin_amdgcn_mfma_f32_16x16x32_bf16(ah[kc - 1], wreg[g][kc], acc[g], 0, 0, 0);

    // update: lane covers rows quad*4+r at its col; all gates in registers
    short* hwr = hb + ((size_t)(t & 1)) * NB * HROW;
    float hn[4];
    #pragma unroll
    for (int r = 0; r < 4; ++r) {
      float ig = __builtin_amdgcn_rcpf(1.f + __expf(-acc[0][r]));
      float fg = __builtin_amdgcn_rcpf(1.f + __expf(-acc[1][r]));
      float gg = fmaxf(acc[2][r], 0.f);
      float og = __builtin_amdgcn_rcpf(1.f + __expf(-acc[3][r]));
      float cn = fg * cst[r] + ig * gg;
      cst[r] = cn;
      hn[r] = og * fmaxf(cn, 0.f);
      short hs = f2bf(hn[r]);
      if (col == 350) hs = (short)0x3F80;        // bias-row input stays 1.0
      else if (col == 351) hs = 0;
      hwr[(quad * 4 + r) * HROW + col] = hs;
    }

    // publish (release store drains the h stores first)
    if (lane == 0)
      __hip_atomic_store(flg + tileg, (uint32_t)(t + 1), __ATOMIC_RELEASE,
                         __HIP_MEMORY_SCOPE_AGENT);

    // dense head AFTER publish, into LDS (keeps vmem queue clean for spin)
    #pragma unroll
    for (int r = 0; r < 4; ++r) {
      float s = hn[r] * dwv;
      s += __shfl_xor(s, 1); s += __shfl_xor(s, 2);
      s += __shfl_xor(s, 4); s += __shfl_xor(s, 8);
      if (l15 == 0) lds_part[wv][t][quad * 4 + r] = s;
    }
  }

  // bulk-store dense partials (once)
  __syncthreads();
  float* wp = wpart + ((size_t)(grp * NCB + j) * NB) * T_;
  for (int i = tid; i < NB * T_; i += 128) {
    int t = i & (T_ - 1), row = i >> 9;
    wp[(size_t)row * T_ + t] = lds_part[0][t][row] + lds_part[1][t][row];
  }
}

// ---- final: out[b,t] = db + sum_j wpart[grp][j][row][t] ----
__global__ void reduce_out(const float* __restrict__ wpart,
                           const float* __restrict__ dense_b,
                           float* __restrict__ out) {
  int i = blockIdx.x * 256 + threadIdx.x;   // i = b*T + t
  int b = i >> 9, t = i & 511;
  int grp = b >> 4, row = b & 15;
  float s = dense_b[0];
  #pragma unroll
  for (int j = 0; j < NCB; ++j)
    s += wpart[(((size_t)grp * NCB + j) * NB + row) * T_ + t];
  out[i] = s;
}

extern "C" void kernel_launch(void* const* d_in, const int* in_sizes, int n_in,
                              void* d_out, int out_size, void* d_ws, size_t ws_size,
                              hipStream_t stream) {
  const float* x    = (const float*)d_in[0];
  const float* kern = (const float*)d_in[1];
  const float* rk   = (const float*)d_in[2];
  const float* bias = (const float*)d_in[3];
  const float* dw   = (const float*)d_in[4];
  const float* db   = (const float*)d_in[5];
  float* out = (float*)d_out;

  char* ws = (char*)d_ws;
  short*    wswz = (short*)(ws);
  short*    xbf  = (short*)(ws + OFF_XBF);
  short*    hbuf = (short*)(ws + OFF_HBUF);
  uint32_t* flags= (uint32_t*)(ws + OFF_FLG);
  float*    wpart= (float*)(ws + OFF_WP);

  prep_w<<<NT, 64, 0, stream>>>(kern, rk, bias, wswz);
  prep_x<<<(256 * T_ * F_) / (256 * 4), 256, 0, stream>>>(x, xbf);
  init_all<<<(NGRP * NB * HROW) / 256, 256, 0, stream>>>(hbuf, flags);
  lstm_kernel<<<NGRP * NCB, 128, 0, stream>>>(xbf, wswz, hbuf, flags, dw, wpart);
  reduce_out<<<(256 * T_) / 256, 256, 0, stream>>>(wpart, db, out);
}

// Round 6
// 2910.584 us; speedup vs baseline: 1.9416x; 1.6722x over previous
//
#include <hip/hip_runtime.h>
#include <stdint.h>

// LSTM B=256,T=512,F=32,U=350; gates i,f,g(relu),o; h=o*relu(c); out=h.dw+db
//
// R6: R4 structure, but ALL cross-block traffic via agent-scope RELAXED
// atomics (= sc1 write-through stores / cache-bypassing loads on gfx950).
//  - R4 evidence: WRITE_SIZE=101MB -> per-step agent release/acquire fences
//    (buffer_wbl2/buffer_inv over a DIRTY L2 holding plain-stored h) forced
//    h through HBM every step. Write-through h => clean L2 => the one
//    release flag store per wave has a no-op wbl2; acquire fence dropped
//    (sc1 loads can't read stale caches) -> workgroup fence for ordering.
//  - No placement assumptions, no inline asm, no XCD checks (R5 post-mortem).
//  - 16 groups x 11 col-blocks (128 thr = 2 waves); wave owns 16 cols x all
//    4 gates; weights register-resident (waves_per_eu(1,1)); gates meet in
//    registers; no barriers in the scan loop.
//  - h stores: lane-pair packed u32 relaxed-agent atomics. h loads: 2xu64
//    relaxed-agent atomics per kc, repacked to short8 A-frags in registers.
//  - Dense head: shfl-reduce -> LDS; bulk store after scan; reduce_out sums.

#define T_   512
#define F_   32
#define U_   350
#define G4   1400
#define NGRP 16
#define NB   16
#define NCB  11
#define KC   12
#define NT   88
#define HROW 352
#define NWV  22          // col-tile waves (flag producers) per group

typedef __attribute__((ext_vector_type(8))) short  short8;
typedef __attribute__((ext_vector_type(4))) short  short4_;
typedef __attribute__((ext_vector_type(4))) float  float4_;
typedef unsigned long long u64t;

__device__ __forceinline__ short f2bf(float f) {
  union { float f; uint32_t u; } v; v.f = f;
  return (short)((v.u + 0x7FFFu + ((v.u >> 16) & 1u)) >> 16);
}

// ---- workspace layout (bytes) ----
#define SZ_W     (NT*KC*64*8*2u)                        // 1,081,344
#define OFF_XBF  (SZ_W)
#define SZ_XBF   (256u*T_*F_*2u)                        // 8,388,608
#define OFF_HBUF (OFF_XBF + SZ_XBF)
#define SZ_HBUF  (NGRP*2u*NB*HROW*2u)                   // 360,448
#define OFF_FLG  (OFF_HBUF + SZ_HBUF)
#define SZ_FLG   (NGRP*64u*4u)                          // 4,096
#define OFF_WP   (OFF_FLG + SZ_FLG)
#define SZ_WP    (NGRP*NCB*NB*T_*4u)                    // 5,767,168

// ---- prep: W_swz[kc][tile][lane][8] bf16 in MFMA B-fragment order ----
__global__ void prep_w(const float* __restrict__ kern,
                       const float* __restrict__ rk,
                       const float* __restrict__ bias,
                       short* __restrict__ wswz) {
  const int tile = blockIdx.x, lane = threadIdx.x;
  const int g = tile / 22, jt = tile % 22;
  const int colg = jt * 16 + (lane & 15);
  const int src = g * U_ + colg;
  const bool valid = (colg < U_);
  const int kbase = (lane >> 4) * 8;
  for (int kc = 0; kc < KC; ++kc) {
    short8 pack;
    #pragma unroll
    for (int jj = 0; jj < 8; ++jj) {
      int k = kc * 32 + kbase + jj;
      float v = 0.f;
      if (valid) {
        if (k < F_)            v = kern[k * G4 + src];
        else if (k < F_ + U_)  v = rk[(k - F_) * G4 + src];
        else if (k == F_ + U_) v = bias[src];
      }
      pack[jj] = f2bf(v);
    }
    *(short8*)(wswz + (((size_t)kc * NT + tile) * 64 + lane) * 8) = pack;
  }
}

// ---- prep: x f32 -> bf16 ([b][t][f], contiguous 16B A-frag loads) ----
__global__ void prep_x(const float* __restrict__ x, short* __restrict__ xbf) {
  int i = (blockIdx.x * 256 + threadIdx.x) * 4;
  float4_ v = *(const float4_*)(x + i);
  short4_ o;
  #pragma unroll
  for (int jj = 0; jj < 4; ++jj) o[jj] = f2bf(v[jj]);
  *(short4_*)(xbf + i) = o;
}

// ---- init: flags=0, hbuf slot1 = h_{-1}=0 (+1.0 at bias col 350) ----
__global__ void init_all(short* __restrict__ hbuf, uint32_t* __restrict__ flags) {
  int i = blockIdx.x * 256 + threadIdx.x;        // 90112 threads
  int c = i % HROW;
  int grp = i / (NB * HROW), rem = i % (NB * HROW);
  hbuf[(grp * 2 + 1) * NB * HROW + rem] = (c == 350) ? (short)0x3F80 : (short)0;
  if (i < NGRP * 64) flags[i] = 0;
}

// ---- main: persistent, 2 decoupled waves per block, weights in regs ----
__global__ __launch_bounds__(128)
__attribute__((amdgpu_waves_per_eu(1, 1)))
void lstm_kernel(const short* __restrict__ xbf, const short* __restrict__ wswz,
                 short* __restrict__ hbuf, uint32_t* __restrict__ flags,
                 const float* __restrict__ dense_w, float* __restrict__ wpart) {
  __shared__ float lds_part[2][T_][16];   // 64 KB dense-head partials

  const int tid  = threadIdx.x;
  const int lane = tid & 63;
  const int wv   = tid >> 6;            // 0..1
  const int l15  = lane & 15;
  const int quad = lane >> 4;
  const int grp  = blockIdx.x & 15;     // XCD-locality heuristic (speed only)
  const int j    = blockIdx.x >> 4;     // 0..10
  const int tileg = 2 * j + wv;         // this wave's col tile 0..21

  // weights -> registers ONCE: 192 regs/lane
  short8 wreg[4][KC];
  #pragma unroll
  for (int g = 0; g < 4; ++g)
    #pragma unroll
    for (int kc = 0; kc < KC; ++kc)
      wreg[g][kc] = *(const short8*)(wswz +
          (((size_t)kc * NT + (g * 22 + tileg)) * 64 + lane) * 8);

  const int col = tileg * 16 + l15;               // gate-relative col 0..351
  const float dwv = (col < U_) ? dense_w[col] : 0.f;
  float cst[4] = {0.f, 0.f, 0.f, 0.f};

  const short* xrow = xbf + ((size_t)(grp * NB + l15) * T_) * F_ + quad * 8;
  short* hb = hbuf + (size_t)grp * 2 * NB * HROW;
  uint32_t* flg = flags + grp * 64;

  #pragma unroll 1
  for (int t = 0; t < T_; ++t) {
    short8 axf = *(const short8*)(xrow + t * F_);

    // kc=0 (x-only) MFMA before the spin — h-independent
    float4_ acc[4];
    #pragma unroll
    for (int g = 0; g < 4; ++g) {
      float4_ z = (float4_){0.f, 0.f, 0.f, 0.f};
      acc[g] = __builtin_amdgcn_mfma_f32_16x16x32_bf16(axf, wreg[g][0], z, 0, 0, 0);
    }

    if (t > 0) {
      const uint32_t tv = (uint32_t)t;
      bool ok;
      do {
        uint32_t v = tv;
        if (lane < NWV)
          v = __hip_atomic_load(flg + lane, __ATOMIC_RELAXED,
                                __HIP_MEMORY_SCOPE_AGENT);
        ok = (bool)__all((int)(v >= tv));
      } while (!ok);
      // ordering only; sc1 data loads below bypass stale caches themselves
      __builtin_amdgcn_fence(__ATOMIC_ACQUIRE, "workgroup");
    }

    // h A-frags from slot (t-1)&1 == (t+1)&1 — relaxed agent u64 loads
    const short* hrd = hb + ((size_t)((t + 1) & 1)) * NB * HROW
                          + (size_t)l15 * HROW + quad * 8;
    short8 ah[KC - 1];
    #pragma unroll
    for (int kc = 1; kc < KC; ++kc) {
      union { u64t q[2]; short8 s; } u;
      const u64t* p = (const u64t*)(hrd + 32 * (kc - 1));
      u.q[0] = __hip_atomic_load(p,     __ATOMIC_RELAXED, __HIP_MEMORY_SCOPE_AGENT);
      u.q[1] = __hip_atomic_load(p + 1, __ATOMIC_RELAXED, __HIP_MEMORY_SCOPE_AGENT);
      ah[kc - 1] = u.s;
    }
    #pragma unroll
    for (int kc = 1; kc < KC; ++kc)
      #pragma unroll
      for (int g = 0; g < 4; ++g)
        acc[g] = __builtin_amdgcn_mfma_f32_16x16x32_bf16(ah[kc - 1], wreg[g][kc], acc[g], 0, 0, 0);

    // update: lane covers rows quad*4+r at its col; gates in registers
    short* hwr = hb + ((size_t)(t & 1)) * NB * HROW;
    float hn[4];
    #pragma unroll
    for (int r = 0; r < 4; ++r) {
      float ig = __builtin_amdgcn_rcpf(1.f + __expf(-acc[0][r]));
      float fg = __builtin_amdgcn_rcpf(1.f + __expf(-acc[1][r]));
      float gg = fmaxf(acc[2][r], 0.f);
      float og = __builtin_amdgcn_rcpf(1.f + __expf(-acc[3][r]));
      float cn = fg * cst[r] + ig * gg;
      cst[r] = cn;
      hn[r] = og * fmaxf(cn, 0.f);
      short hs = f2bf(hn[r]);
      if (col == 350) hs = (short)0x3F80;        // bias-row input stays 1.0
      else if (col == 351) hs = 0;
      // pack lane pairs (cols c,c+1) -> u32 write-through store by even lane
      int hv = (int)(unsigned short)hs;
      int pv = __shfl_xor(hv, 1);
      if ((l15 & 1) == 0) {
        uint32_t word = (uint32_t)(unsigned short)hv | ((uint32_t)pv << 16);
        uint32_t* dst = (uint32_t*)(hwr + (quad * 4 + r) * HROW + col);
        __hip_atomic_store(dst, word, __ATOMIC_RELAXED,
                           __HIP_MEMORY_SCOPE_AGENT);
      }
    }

    // publish (release orders this wave's h stores; wbl2 is cheap: L2 clean)
    if (lane == 0)
      __hip_atomic_store(flg + tileg, (uint32_t)(t + 1), __ATOMIC_RELEASE,
                         __HIP_MEMORY_SCOPE_AGENT);

    // dense head AFTER publish, into LDS (off the critical path)
    #pragma unroll
    for (int r = 0; r < 4; ++r) {
      float s = hn[r] * dwv;
      s += __shfl_xor(s, 1); s += __shfl_xor(s, 2);
      s += __shfl_xor(s, 4); s += __shfl_xor(s, 8);
      if (l15 == 0) lds_part[wv][t][quad * 4 + r] = s;
    }
  }

  // bulk-store dense partials (once)
  __syncthreads();
  float* wp = wpart + ((size_t)(grp * NCB + j) * NB) * T_;
  for (int i = tid; i < NB * T_; i += 128) {
    int t = i & (T_ - 1), row = i >> 9;
    wp[(size_t)row * T_ + t] = lds_part[0][t][row] + lds_part[1][t][row];
  }
}

// ---- final: out[b,t] = db + sum_j wpart[grp][j][row][t] ----
__global__ void reduce_out(const float* __restrict__ wpart,
                           const float* __restrict__ dense_b,
                           float* __restrict__ out) {
  int i = blockIdx.x * 256 + threadIdx.x;   // i = b*T + t
  int b = i >> 9, t = i & 511;
  int grp = b >> 4, row = b & 15;
  float s = dense_b[0];
  #pragma unroll
  for (int j = 0; j < NCB; ++j)
    s += wpart[(((size_t)grp * NCB + j) * NB + row) * T_ + t];
  out[i] = s;
}

extern "C" void kernel_launch(void* const* d_in, const int* in_sizes, int n_in,
                              void* d_out, int out_size, void* d_ws, size_t ws_size,
                              hipStream_t stream) {
  const float* x    = (const float*)d_in[0];
  const float* kern = (const float*)d_in[1];
  const float* rk   = (const float*)d_in[2];
  const float* bias = (const float*)d_in[3];
  const float* dw   = (const float*)d_in[4];
  const float* db   = (const float*)d_in[5];
  float* out = (float*)d_out;

  char* ws = (char*)d_ws;
  short*    wswz = (short*)(ws);
  short*    xbf  = (short*)(ws + OFF_XBF);
  short*    hbuf = (short*)(ws + OFF_HBUF);
  uint32_t* flags= (uint32_t*)(ws + OFF_FLG);
  float*    wpart= (float*)(ws + OFF_WP);

  prep_w<<<NT, 64, 0, stream>>>(kern, rk, bias, wswz);
  prep_x<<<(256 * T_ * F_) / (256 * 4), 256, 0, stream>>>(x, xbf);
  init_all<<<(NGRP * NB * HROW) / 256, 256, 0, stream>>>(hbuf, flags);
  lstm_kernel<<<NGRP * NCB, 128, 0, stream>>>(xbf, wswz, hbuf, flags, dw, wpart);
  reduce_out<<<(256 * T_) / 256, 256, 0, stream>>>(wpart, db, out);
}

// Round 7
// 2762.188 us; speedup vs baseline: 2.0459x; 1.0537x over previous
//
#include <hip/hip_runtime.h>
#include <stdint.h>

// LSTM B=256,T=512,F=32,U=350; gates i,f,g(relu),o; h=o*relu(c); out=h.dw+db
//
// R7: self-validating h exchange — tag-in-word protocol, zero fences/flags.
//  - h stored as f32 words: hi16 = RNE bf16 of h (what MFMA consumes),
//    lo16 = step tag (t+1). Word-atomic => consumer's data loads ARE the
//    sync: load A-frag words, verify every tag == t, retry on any stale.
//  - Producer: fire-and-forget relaxed-agent u32 stores. No vmcnt wait, no
//    release/wbl2, no flag. Consumer: no poll phase, no acquire fence.
//  - Ping-pong depth 2 sound: writer of tag t+3 to a slot starts only after
//    all blocks' tag-(t+2) writes, which postdate all tag-(t+1) reads of
//    that slot (proof in journal). Tags 0..512 unique in lo16.
//  - Rest as R6: 16 groups x 11 col-blocks (2 waves, 128 thr); wave owns
//    16 cols x all 4 gates; weights register-resident (waves_per_eu(1,1));
//    gates meet in registers; no barriers in the scan loop; dense head via
//    LDS partials + reduce_out.

#define T_   512
#define F_   32
#define U_   350
#define G4   1400
#define NGRP 16
#define NB   16
#define NCB  11
#define KC   12
#define NT   88
#define HROW 352         // f32 words per h row (350 + bias-1.0 col + zero col)

typedef __attribute__((ext_vector_type(8))) short  short8;
typedef __attribute__((ext_vector_type(4))) short  short4_;
typedef __attribute__((ext_vector_type(4))) float  float4_;
typedef unsigned long long u64t;

__device__ __forceinline__ short f2bf(float f) {
  union { float f; uint32_t u; } v; v.f = f;
  return (short)((v.u + 0x7FFFu + ((v.u >> 16) & 1u)) >> 16);
}

// ---- workspace layout (bytes) ----
#define SZ_W     (NT*KC*64*8*2u)                        // 1,081,344
#define OFF_XBF  (SZ_W)
#define SZ_XBF   (256u*T_*F_*2u)                        // 8,388,608
#define OFF_HBUF (OFF_XBF + SZ_XBF)
#define SZ_HBUF  (NGRP*2u*NB*HROW*4u)                   // 720,896 (f32 words)
#define OFF_WP   (OFF_HBUF + SZ_HBUF)
#define SZ_WP    (NGRP*NCB*NB*T_*4u)                    // 5,767,168

// ---- prep: W_swz[kc][tile][lane][8] bf16 in MFMA B-fragment order ----
__global__ void prep_w(const float* __restrict__ kern,
                       const float* __restrict__ rk,
                       const float* __restrict__ bias,
                       short* __restrict__ wswz) {
  const int tile = blockIdx.x, lane = threadIdx.x;
  const int g = tile / 22, jt = tile % 22;
  const int colg = jt * 16 + (lane & 15);
  const int src = g * U_ + colg;
  const bool valid = (colg < U_);
  const int kbase = (lane >> 4) * 8;
  for (int kc = 0; kc < KC; ++kc) {
    short8 pack;
    #pragma unroll
    for (int jj = 0; jj < 8; ++jj) {
      int k = kc * 32 + kbase + jj;
      float v = 0.f;
      if (valid) {
        if (k < F_)            v = kern[k * G4 + src];
        else if (k < F_ + U_)  v = rk[(k - F_) * G4 + src];
        else if (k == F_ + U_) v = bias[src];
      }
      pack[jj] = f2bf(v);
    }
    *(short8*)(wswz + (((size_t)kc * NT + tile) * 64 + lane) * 8) = pack;
  }
}

// ---- prep: x f32 -> bf16 ([b][t][f], contiguous 16B A-frag loads) ----
__global__ void prep_x(const float* __restrict__ x, short* __restrict__ xbf) {
  int i = (blockIdx.x * 256 + threadIdx.x) * 4;
  float4_ v = *(const float4_*)(x + i);
  short4_ o;
  #pragma unroll
  for (int jj = 0; jj < 4; ++jj) o[jj] = f2bf(v[jj]);
  *(short4_*)(xbf + i) = o;
}

// ---- init: hbuf slot1 = h_{-1}=0 with tag 0 (bias col 350 = bf16 1.0) ----
// Slot 0 needs no init: step-1 readers expect tag 1 and retry over poison.
__global__ void init_all(uint32_t* __restrict__ hbuf32) {
  int i = blockIdx.x * 256 + threadIdx.x;        // 90112 threads
  int c = i % HROW;
  int grp = i / (NB * HROW), rem = i % (NB * HROW);
  hbuf32[(grp * 2 + 1) * NB * HROW + rem] =
      (c == 350) ? 0x3F800000u : 0u;
}

// ---- main: persistent, 2 decoupled waves per block, weights in regs ----
__global__ __launch_bounds__(128)
__attribute__((amdgpu_waves_per_eu(1, 1)))
void lstm_kernel(const short* __restrict__ xbf, const short* __restrict__ wswz,
                 uint32_t* __restrict__ hbuf32,
                 const float* __restrict__ dense_w, float* __restrict__ wpart) {
  __shared__ float lds_part[2][T_][16];   // 64 KB dense-head partials

  const int tid  = threadIdx.x;
  const int lane = tid & 63;
  const int wv   = tid >> 6;            // 0..1
  const int l15  = lane & 15;
  const int quad = lane >> 4;
  const int grp  = blockIdx.x & 15;     // XCD-locality heuristic (speed only)
  const int j    = blockIdx.x >> 4;     // 0..10
  const int tileg = 2 * j + wv;         // this wave's col tile 0..21

  // weights -> registers ONCE: 192 regs/lane
  short8 wreg[4][KC];
  #pragma unroll
  for (int g = 0; g < 4; ++g)
    #pragma unroll
    for (int kc = 0; kc < KC; ++kc)
      wreg[g][kc] = *(const short8*)(wswz +
          (((size_t)kc * NT + (g * 22 + tileg)) * 64 + lane) * 8);

  const int col = tileg * 16 + l15;               // gate-relative col 0..351
  const float dwv = (col < U_) ? dense_w[col] : 0.f;
  float cst[4] = {0.f, 0.f, 0.f, 0.f};

  const short* xrow = xbf + ((size_t)(grp * NB + l15) * T_) * F_ + quad * 8;
  uint32_t* hb = hbuf32 + (size_t)grp * 2 * NB * HROW;

  #pragma unroll 1
  for (int t = 0; t < T_; ++t) {
    short8 axf = *(const short8*)(xrow + t * F_);

    // kc=0 (x-only) MFMA — h-independent, overlaps first h-load flight
    float4_ acc[4];
    #pragma unroll
    for (int g = 0; g < 4; ++g) {
      float4_ z = (float4_){0.f, 0.f, 0.f, 0.f};
      acc[g] = __builtin_amdgcn_mfma_f32_16x16x32_bf16(axf, wreg[g][0], z, 0, 0, 0);
    }

    // tag-verified h A-frag load from slot (t-1)&1 == (t+1)&1
    // lane covers row l15, h cols (kc-1)*32 + quad*8 .. +8  (as f32 words)
    const uint32_t tag = (uint32_t)t & 0xFFFFu;
    const uint32_t* hq = hb + ((size_t)((t + 1) & 1)) * NB * HROW
                            + (size_t)l15 * HROW + quad * 8;
    u64t q[44];
    bool okall;
    do {
      #pragma unroll
      for (int i = 0; i < 11; ++i) {
        const u64t* p = (const u64t*)(hq + i * 32);
        q[4 * i + 0] = __hip_atomic_load(p + 0, __ATOMIC_RELAXED, __HIP_MEMORY_SCOPE_AGENT);
        q[4 * i + 1] = __hip_atomic_load(p + 1, __ATOMIC_RELAXED, __HIP_MEMORY_SCOPE_AGENT);
        q[4 * i + 2] = __hip_atomic_load(p + 2, __ATOMIC_RELAXED, __HIP_MEMORY_SCOPE_AGENT);
        q[4 * i + 3] = __hip_atomic_load(p + 3, __ATOMIC_RELAXED, __HIP_MEMORY_SCOPE_AGENT);
      }
      uint32_t bad = 0;
      #pragma unroll
      for (int i = 0; i < 44; ++i) {
        bad |= ((uint32_t)q[i] ^ tag) & 0xFFFFu;
        bad |= ((uint32_t)(q[i] >> 32) ^ tag) & 0xFFFFu;
      }
      okall = (bool)__all((int)(bad == 0));
    } while (!okall);

    // repack hi16 pairs -> bf16 A-frags; MFMA over kc=1..11
    #pragma unroll
    for (int i = 0; i < 11; ++i) {
      union { uint32_t w[4]; short8 s; } u;
      #pragma unroll
      for (int k = 0; k < 4; ++k) {
        uint32_t lo = (uint32_t)q[4 * i + k];
        uint32_t hi = (uint32_t)(q[4 * i + k] >> 32);
        u.w[k] = (lo >> 16) | (hi & 0xFFFF0000u);
      }
      #pragma unroll
      for (int g = 0; g < 4; ++g)
        acc[g] = __builtin_amdgcn_mfma_f32_16x16x32_bf16(u.s, wreg[g][i + 1], acc[g], 0, 0, 0);
    }

    // update: lane covers rows quad*4+r at its col; gates in registers
    uint32_t* hwr = hb + ((size_t)(t & 1)) * NB * HROW;
    const uint32_t otag = (uint32_t)(t + 1) & 0xFFFFu;
    float hn[4];
    #pragma unroll
    for (int r = 0; r < 4; ++r) {
      float ig = __builtin_amdgcn_rcpf(1.f + __expf(-acc[0][r]));
      float fg = __builtin_amdgcn_rcpf(1.f + __expf(-acc[1][r]));
      float gg = fmaxf(acc[2][r], 0.f);
      float og = __builtin_amdgcn_rcpf(1.f + __expf(-acc[3][r]));
      float cn = fg * cst[r] + ig * gg;
      cst[r] = cn;
      hn[r] = og * fmaxf(cn, 0.f);
      short hs = f2bf(hn[r]);
      if (col == 350) hs = (short)0x3F80;        // bias-row input stays 1.0
      else if (col == 351) hs = 0;
      uint32_t word = ((uint32_t)(unsigned short)hs << 16) | otag;
      __hip_atomic_store(hwr + (quad * 4 + r) * HROW + col, word,
                         __ATOMIC_RELAXED, __HIP_MEMORY_SCOPE_AGENT);
    }

    // dense head (off the critical path), into LDS
    #pragma unroll
    for (int r = 0; r < 4; ++r) {
      float s = hn[r] * dwv;
      s += __shfl_xor(s, 1); s += __shfl_xor(s, 2);
      s += __shfl_xor(s, 4); s += __shfl_xor(s, 8);
      if (l15 == 0) lds_part[wv][t][quad * 4 + r] = s;
    }
  }

  // bulk-store dense partials (once)
  __syncthreads();
  float* wp = wpart + ((size_t)(grp * NCB + j) * NB) * T_;
  for (int i = tid; i < NB * T_; i += 128) {
    int t = i & (T_ - 1), row = i >> 9;
    wp[(size_t)row * T_ + t] = lds_part[0][t][row] + lds_part[1][t][row];
  }
}

// ---- final: out[b,t] = db + sum_j wpart[grp][j][row][t] ----
__global__ void reduce_out(const float* __restrict__ wpart,
                           const float* __restrict__ dense_b,
                           float* __restrict__ out) {
  int i = blockIdx.x * 256 + threadIdx.x;   // i = b*T + t
  int b = i >> 9, t = i & 511;
  int grp = b >> 4, row = b & 15;
  float s = dense_b[0];
  #pragma unroll
  for (int j = 0; j < NCB; ++j)
    s += wpart[(((size_t)grp * NCB + j) * NB + row) * T_ + t];
  out[i] = s;
}

extern "C" void kernel_launch(void* const* d_in, const int* in_sizes, int n_in,
                              void* d_out, int out_size, void* d_ws, size_t ws_size,
                              hipStream_t stream) {
  const float* x    = (const float*)d_in[0];
  const float* kern = (const float*)d_in[1];
  const float* rk   = (const float*)d_in[2];
  const float* bias = (const float*)d_in[3];
  const float* dw   = (const float*)d_in[4];
  const float* db   = (const float*)d_in[5];
  float* out = (float*)d_out;

  char* ws = (char*)d_ws;
  short*    wswz   = (short*)(ws);
  short*    xbf    = (short*)(ws + OFF_XBF);
  uint32_t* hbuf32 = (uint32_t*)(ws + OFF_HBUF);
  float*    wpart  = (float*)(ws + OFF_WP);

  prep_w<<<NT, 64, 0, stream>>>(kern, rk, bias, wswz);
  prep_x<<<(256 * T_ * F_) / (256 * 4), 256, 0, stream>>>(x, xbf);
  init_all<<<(NGRP * NB * HROW) / 256, 256, 0, stream>>>(hbuf32);
  lstm_kernel<<<NGRP * NCB, 128, 0, stream>>>(xbf, wswz, hbuf32, dw, wpart);
  reduce_out<<<(256 * T_) / 256, 256, 0, stream>>>(wpart, db, out);
}